// Round 1
// baseline (445.621 us; speedup 1.0000x reference)
//
#include <hip/hip_runtime.h>

#define TB      64      // samples per block (== wavefront size; lane = sample)
#define THREADS 512     // 8 waves
#define EMB     64
#define UFEAT   21
#define IFEAT   39
#define KXU     85      // EMB + UFEAT
#define KXI     103     // EMB + IFEAT
#define HW      128     // 2*EMB
#define HID     256
// LDS row strides: odd -> lane*stride spans all 32 banks, column reads conflict-free
#define XU_S    89
#define XI_S    105
#define H_S     129

template<int K, int S>
__device__ __forceinline__ void layer_in(const float (*__restrict__ X)[S], int lane, int o0,
                                         const float* __restrict__ W,
                                         const float* __restrict__ b,
                                         float (*__restrict__ H)[H_S], int hoff)
{
    float acc[16];
    const float* x = X[lane];
    // init: bias + raw-embedding residual (x[0..63] holds the raw embedding)
    #pragma unroll
    for (int j = 0; j < 16; ++j) acc[j] = b[o0 + j] + x[o0 + j];
    // dot over relu(concat(emb, feat)); weights are wave-uniform -> scalar loads
    #pragma unroll 4
    for (int k = 0; k < K; ++k) {
        const float a = fmaxf(x[k], 0.f);
        #pragma unroll
        for (int j = 0; j < 16; ++j)
            acc[j] = fmaf(a, W[(o0 + j) * K + k], acc[j]);
    }
    #pragma unroll
    for (int j = 0; j < 16; ++j)
        H[lane][hoff + o0 + j] = fmaxf(acc[j], 0.f);   // h = relu(concat(uh, ih))
}

__global__ __launch_bounds__(THREADS, 1)
void rec_fused(const int*   __restrict__ user_id,  const int*   __restrict__ item_id,
               const float* __restrict__ user_feat, const float* __restrict__ item_feat,
               const float* __restrict__ user_emb,  const float* __restrict__ item_emb,
               const float* __restrict__ W_uf, const float* __restrict__ b_uf,
               const float* __restrict__ W_if, const float* __restrict__ b_if,
               const float* __restrict__ W1,  const float* __restrict__ b1,
               const float* __restrict__ W2,  const float* __restrict__ b2,
               float* __restrict__ out)
{
    __shared__ float sXU[TB][XU_S];   // raw ue || user_feat
    __shared__ float sXI[TB][XI_S];   // raw ie || item_feat
    __shared__ float sH [TB][H_S];    // relu'd hidden (128)
    __shared__ float sOut[8][TB];     // per-wave partial outputs

    const int t  = threadIdx.x;
    const int s0 = blockIdx.x * TB;

    // ---- stage: embedding gathers (256 B contiguous per row, float4 chunks) ----
    #pragma unroll 2
    for (int i = t; i < TB * (EMB / 4); i += THREADS) {
        const int r = i >> 4, c = (i & 15) * 4;
        const int uid = user_id[s0 + r];
        const float4 v = *reinterpret_cast<const float4*>(user_emb + uid * EMB + c);
        sXU[r][c] = v.x; sXU[r][c + 1] = v.y; sXU[r][c + 2] = v.z; sXU[r][c + 3] = v.w;
    }
    #pragma unroll 2
    for (int i = t; i < TB * (EMB / 4); i += THREADS) {
        const int r = i >> 4, c = (i & 15) * 4;
        const int iid = item_id[s0 + r];
        const float4 v = *reinterpret_cast<const float4*>(item_emb + iid * EMB + c);
        sXI[r][c] = v.x; sXI[r][c + 1] = v.y; sXI[r][c + 2] = v.z; sXI[r][c + 3] = v.w;
    }
    // ---- stage: dense features (fully coalesced) ----
    for (int i = t; i < TB * UFEAT; i += THREADS)
        sXU[i / UFEAT][EMB + i % UFEAT] = user_feat[s0 * UFEAT + i];
    for (int i = t; i < TB * IFEAT; i += THREADS)
        sXI[i / IFEAT][EMB + i % IFEAT] = item_feat[s0 * IFEAT + i];
    __syncthreads();

    const int wave = __builtin_amdgcn_readfirstlane(t >> 6);  // uniform -> scalar weight loads
    const int lane = t & 63;

    // ---- layers 1&2: waves 0-3 user (outputs 0..63), waves 4-7 item (outputs 64..127) ----
    if (wave < 4) layer_in<KXU, XU_S>(sXU, lane, wave * 16,       W_uf, b_uf, sH, 0);
    else          layer_in<KXI, XI_S>(sXI, lane, (wave - 4) * 16, W_if, b_if, sH, EMB);
    __syncthreads();

    // ---- layer 3 (+ fused 256->1 head): each wave owns 32 hidden outputs ----
    {
        const int o0 = wave * 32;
        float acc[32];
        #pragma unroll
        for (int j = 0; j < 32; ++j) acc[j] = b1[o0 + j];
        const float* h = sH[lane];
        #pragma unroll 2
        for (int k = 0; k < HW; ++k) {
            const float a = h[k];
            #pragma unroll
            for (int j = 0; j < 32; ++j)
                acc[j] = fmaf(a, W1[(o0 + j) * HW + k], acc[j]);
        }
        float op = 0.f;
        #pragma unroll
        for (int j = 0; j < 32; ++j)
            op += fmaxf(acc[j], 0.f) * W2[o0 + j];
        sOut[wave][lane] = op;
    }
    __syncthreads();

    // ---- reduce 8 wave-partials per sample ----
    if (t < TB) {
        float r = b2[0];
        #pragma unroll
        for (int w = 0; w < 8; ++w) r += sOut[w][t];
        out[s0 + t] = r;
    }
}

extern "C" void kernel_launch(void* const* d_in, const int* in_sizes, int n_in,
                              void* d_out, int out_size, void* d_ws, size_t ws_size,
                              hipStream_t stream) {
    const int*   user_id   = (const int*)  d_in[0];
    const int*   item_id   = (const int*)  d_in[1];
    const float* user_feat = (const float*)d_in[2];
    const float* item_feat = (const float*)d_in[3];
    const float* user_emb  = (const float*)d_in[4];
    const float* item_emb  = (const float*)d_in[5];
    const float* W_uf      = (const float*)d_in[6];
    const float* b_uf      = (const float*)d_in[7];
    const float* W_if      = (const float*)d_in[8];
    const float* b_if      = (const float*)d_in[9];
    const float* W1        = (const float*)d_in[10];
    const float* b1        = (const float*)d_in[11];
    const float* W2        = (const float*)d_in[12];
    const float* b2        = (const float*)d_in[13];
    float* out = (float*)d_out;

    const int blocks = 16384 / TB;   // 256
    rec_fused<<<blocks, THREADS, 0, stream>>>(
        user_id, item_id, user_feat, item_feat, user_emb, item_emb,
        W_uf, b_uf, W_if, b_if, W1, b1, W2, b2, out);
}

// Round 5
// 408.180 us; speedup vs baseline: 1.0917x; 1.0917x over previous
//
#include <hip/hip_runtime.h>

#define TB      64      // samples per block (== wavefront; lane = sample)
#define THREADS 1024    // 16 waves -> 4 waves/SIMD (was 2)
#define NWAVE   16
#define EMB     64
#define UFEAT   21
#define IFEAT   39
#define KXU     85      // EMB + UFEAT
#define KXI     103     // EMB + IFEAT
#define HW      128     // 2*EMB
// odd row strides -> lane*stride hits all 32 banks; column-broadcast reads are 2-way (free)
#define XU_S    89
#define XI_S    105
#define H_S     129

template<int K>
__device__ __forceinline__ void layer8(const float* __restrict__ x, int o0,
                                       const float* __restrict__ W,
                                       const float* __restrict__ b,
                                       float acc[8])
{
    // init: bias + raw-embedding residual (x[0..63] = raw embedding)
    #pragma unroll
    for (int j = 0; j < 8; ++j) acc[j] = b[o0 + j] + x[o0 + j];
    // dot over relu(concat(emb, feat)); W addresses are wave-uniform -> s_load
    #pragma unroll 4
    for (int k = 0; k < K; ++k) {
        const float a = fmaxf(x[k], 0.f);
        #pragma unroll
        for (int j = 0; j < 8; ++j)
            acc[j] = fmaf(a, W[(o0 + j) * K + k], acc[j]);
    }
}

__global__ __launch_bounds__(THREADS, 4)
void rec_fused(const int*   __restrict__ user_id,  const int*   __restrict__ item_id,
               const float* __restrict__ user_feat, const float* __restrict__ item_feat,
               const float* __restrict__ user_emb,  const float* __restrict__ item_emb,
               const float* __restrict__ W_uf, const float* __restrict__ b_uf,
               const float* __restrict__ W_if, const float* __restrict__ b_if,
               const float* __restrict__ W1,  const float* __restrict__ b1,
               const float* __restrict__ W2,  const float* __restrict__ b2,
               float* __restrict__ out)
{
    // X staging and H (hidden) alias the same LDS: H (64*129 floats) fits inside
    // X (64*(89+105) floats); H is written only after all X reads complete.
    __shared__ float smem[TB * XU_S + TB * XI_S];   // 49664 B
    __shared__ float sOut[NWAVE][TB];               // 4096 B  -> 52.5 KB total

    const int t  = threadIdx.x;
    const int s0 = blockIdx.x * TB;
    float* sXU = smem;                 // row stride XU_S
    float* sXI = smem + TB * XU_S;     // row stride XI_S

    // ---- stage embeddings: 1024 threads, one float4 per table each; user+item
    // issued back-to-back so their HBM latencies overlap ----
    {
        const int r = t >> 4, c = (t & 15) << 2;
        const int uid = user_id[s0 + r];
        const int iid = item_id[s0 + r];
        const float4 u = *reinterpret_cast<const float4*>(user_emb + uid * EMB + c);
        const float4 v = *reinterpret_cast<const float4*>(item_emb + iid * EMB + c);
        float* pu = sXU + r * XU_S + c;
        pu[0] = u.x; pu[1] = u.y; pu[2] = u.z; pu[3] = u.w;
        float* pi = sXI + r * XI_S + c;
        pi[0] = v.x; pi[1] = v.y; pi[2] = v.z; pi[3] = v.w;
    }
    // ---- stage dense features (coalesced) ----
    for (int i = t; i < TB * UFEAT; i += THREADS)
        sXU[(i / UFEAT) * XU_S + EMB + i % UFEAT] = user_feat[s0 * UFEAT + i];
    for (int i = t; i < TB * IFEAT; i += THREADS)
        sXI[(i / IFEAT) * XI_S + EMB + i % IFEAT] = item_feat[s0 * IFEAT + i];
    __syncthreads();

    const int wave = __builtin_amdgcn_readfirstlane(t >> 6);  // uniform -> scalar weight loads
    const int lane = t & 63;

    // ---- layers 1&2: waves 0-7 user (8 outputs each), waves 8-15 item ----
    float acc[8];
    if (wave < 8) layer8<KXU>(sXU + lane * XU_S, wave * 8,       W_uf, b_uf, acc);
    else          layer8<KXI>(sXI + lane * XI_S, (wave - 8) * 8, W_if, b_if, acc);
    __syncthreads();                       // all X reads done -> safe to overwrite with H

    {
        float* Hrow = smem + lane * H_S;
        const int hoff = (wave < 8) ? wave * 8 : EMB + (wave - 8) * 8;
        #pragma unroll
        for (int j = 0; j < 8; ++j) Hrow[hoff + j] = fmaxf(acc[j], 0.f);
    }
    __syncthreads();

    // ---- layer 3 (+ fused 256->1 head): each wave owns 16 hidden outputs ----
    {
        const int o0 = wave * 16;
        float a3[16];
        #pragma unroll
        for (int j = 0; j < 16; ++j) a3[j] = b1[o0 + j];
        const float* h = smem + lane * H_S;
        #pragma unroll 4
        for (int k = 0; k < HW; ++k) {
            const float a = h[k];
            #pragma unroll
            for (int j = 0; j < 16; ++j)
                a3[j] = fmaf(a, W1[(o0 + j) * HW + k], a3[j]);
        }
        float op = 0.f;
        #pragma unroll
        for (int j = 0; j < 16; ++j)
            op = fmaf(fmaxf(a3[j], 0.f), W2[o0 + j], op);
        sOut[wave][lane] = op;
    }
    __syncthreads();

    // ---- reduce 16 wave-partials per sample ----
    if (t < TB) {
        float r = b2[0];
        #pragma unroll
        for (int w = 0; w < NWAVE; ++w) r += sOut[w][t];
        out[s0 + t] = r;
    }
}

extern "C" void kernel_launch(void* const* d_in, const int* in_sizes, int n_in,
                              void* d_out, int out_size, void* d_ws, size_t ws_size,
                              hipStream_t stream) {
    const int*   user_id   = (const int*)  d_in[0];
    const int*   item_id   = (const int*)  d_in[1];
    const float* user_feat = (const float*)d_in[2];
    const float* item_feat = (const float*)d_in[3];
    const float* user_emb  = (const float*)d_in[4];
    const float* item_emb  = (const float*)d_in[5];
    const float* W_uf      = (const float*)d_in[6];
    const float* b_uf      = (const float*)d_in[7];
    const float* W_if      = (const float*)d_in[8];
    const float* b_if      = (const float*)d_in[9];
    const float* W1        = (const float*)d_in[10];
    const float* b1        = (const float*)d_in[11];
    const float* W2        = (const float*)d_in[12];
    const float* b2        = (const float*)d_in[13];
    float* out = (float*)d_out;

    const int blocks = 16384 / TB;   // 256 = one block per CU
    rec_fused<<<blocks, THREADS, 0, stream>>>(
        user_id, item_id, user_feat, item_feat, user_emb, item_emb,
        W_uf, b_uf, W_if, b_if, W1, b1, W2, b2, out);
}